// Round 4
// baseline (337.940 us; speedup 1.0000x reference)
//
#include <hip/hip_runtime.h>
#include <cstdint>
#include <cstddef>

#define NSPIN 2
#define NPART 16
#define DDIM  512
#define NION  8

// LDS float offsets (total 13376 floats = 53504 B -> 3 blocks/CU)
#define RS_OFF    8192                    // bf16 W fragments occupy [0,8192) floats = 32 KB
#define LINP_OFF  (RS_OFF + 1536)        // RS: [ib][e(24)][j(16)] = 1536
#define LINJ_OFF  (LINP_OFF + 1024)      // LINP: [ib][p][k] stride 16
#define ENV_OFF   (LINJ_OFF + 1280)      // LINJ: [ib][j][k] stride 20
#define DETS_OFF  (ENV_OFF + 1280)       // ENV:  [ib][j][k] stride 20
#define LDS_FLOATS (DETS_OFF + 64)
#define LDS_BYTES  (LDS_FLOATS * 4)      // 53504 B

typedef short bf16x8 __attribute__((ext_vector_type(8)));
typedef float f32x4  __attribute__((ext_vector_type(4)));

__device__ __forceinline__ short bfc(float x) {  // f32 -> bf16 (RNE)
    unsigned u = __float_as_uint(x);
    u += 0x7FFFu + ((u >> 16) & 1u);
    return (short)(u >> 16);
}

// 16-lane-row rotate + unsigned max (VALU pipe)
#define DPPMAXU(k, ctrl) { unsigned o_ = (unsigned)__builtin_amdgcn_update_dpp(0, (int)(k), (ctrl), 0xF, 0xF, true); (k) = (k) > o_ ? (k) : o_; }

__global__ void __launch_bounds__(256, 3)
ppdet_kernel(const float* __restrict__ EQ, const float* __restrict__ RE,
             const float* __restrict__ WL, const float* __restrict__ BL,
             const float* __restrict__ AE, const float* __restrict__ WI,
             float* __restrict__ OUT)
{
    extern __shared__ float ls[];
    const int t  = threadIdx.x;
    const int s  = blockIdx.x >> 9;           // spin
    const int b0 = (blockIdx.x & 511) * 4;    // 4 b's per block

    const int l  = t & 63;                    // lane in wave
    const int w  = t >> 6;                    // wave id (0..3)
    const int c  = l & 15;                    // MFMA row/col lane index
    const int h4 = l >> 4;                    // MFMA k-group
    const int jr = t & 15;                    // row index (env/det)
    const int ke = t >> 4;                    // k-column slot (env) / matrix p (det)

    // ---- stage W as bf16 MFMA B-fragments: slot = (half*16+ks)*64+lane ----
    {
        const float* Wg = WL + (size_t)s * (2 * DDIM * NPART);
        ushort* wb = (ushort*)ls;
        #pragma unroll
        for (int it = 0; it < 8; ++it) {
            int slot = it * 256 + t;              // 0..2047
            int half = slot >> 10;
            int ks   = (slot >> 6) & 15;
            int lane = slot & 63;
            int cc2  = lane & 15, hh = lane >> 4;
            const float* src = Wg + ((size_t)(half * 512 + ks * 32 + hh * 8)) * NPART + cc2;
            ushort u[8];
            #pragma unroll
            for (int e = 0; e < 8; ++e) u[e] = (ushort)bfc(src[e * NPART]);
            uint4 pk;
            pk.x = (unsigned)u[0] | ((unsigned)u[1] << 16);
            pk.y = (unsigned)u[2] | ((unsigned)u[3] << 16);
            pk.z = (unsigned)u[4] | ((unsigned)u[5] << 16);
            pk.w = (unsigned)u[6] | ((unsigned)u[7] << 16);
            *(uint4*)&wb[slot * 8] = pk;
        }
    }
    // ---- stage r_ei transposed: RS[ib][e][j], lane-linear writes ----
    #pragma unroll
    for (int it = 0; it < 6; ++it) {
        int idx = it * 256 + t;                   // 0..1535 = ib*384 + e*16 + j
        int bi = idx / 384, rem = idx % 384;
        int e = rem >> 4, j = rem & 15;
        ls[RS_OFF + idx] = RE[((size_t)(b0 + bi) * 32 + s * 16 + j) * 24 + e];
    }
    __syncthreads();   // barrier 1: W + RS staged

    // ---- GEMM via MFMA: wave w handles b = b0+w ----
    {
        const float* xg = EQ + ((size_t)(b0 + w) * 32 + s * 16 + c) * DDIM + h4 * 8;
        const ushort* wb = (const ushort*)ls;
        f32x4 accp = {0.f, 0.f, 0.f, 0.f}, accj = {0.f, 0.f, 0.f, 0.f};
        #pragma unroll
        for (int ks = 0; ks < 16; ++ks) {
            float4 a0 = *(const float4*)(xg + ks * 32);
            float4 a1 = *(const float4*)(xg + ks * 32 + 4);
            bf16x8 af;
            af[0] = bfc(a0.x); af[1] = bfc(a0.y); af[2] = bfc(a0.z); af[3] = bfc(a0.w);
            af[4] = bfc(a1.x); af[5] = bfc(a1.y); af[6] = bfc(a1.z); af[7] = bfc(a1.w);
            bf16x8 bf1 = *(const bf16x8*)(wb + (size_t)(ks * 64 + l) * 8);
            bf16x8 bf2 = *(const bf16x8*)(wb + (size_t)((16 + ks) * 64 + l) * 8);
            accp = __builtin_amdgcn_mfma_f32_16x16x32_bf16(af, bf1, accp, 0, 0, 0);
            accj = __builtin_amdgcn_mfma_f32_16x16x32_bf16(af, bf2, accj, 0, 0, 0);
        }
        const float blv = BL[s * NPART + c];
        #pragma unroll
        for (int q = 0; q < 4; ++q) {     // C: row = h4*4+q, col = c
            ls[LINP_OFF + (w * 16 + h4 * 4 + q) * 16 + c] = accp[q];
            ls[LINJ_OFF + (w * 16 + h4 * 4 + q) * 20 + c] = accj[q] + blv;
        }
    }

    // ---- env: Gram trick, G = A^T A per (ion, ke); RS reads conflict-free ----
    {
        float G0[8], G1[8], G2[8], G3[8], G4[8], G5[8], wir[8];
        const float* Ag = AE + (size_t)s * (9 * NION * NPART);
        #pragma unroll
        for (int i = 0; i < 8; ++i) {
            float a00 = Ag[((0 * 3 + 0) * NION + i) * NPART + ke];
            float a01 = Ag[((0 * 3 + 1) * NION + i) * NPART + ke];
            float a02 = Ag[((0 * 3 + 2) * NION + i) * NPART + ke];
            float a10 = Ag[((1 * 3 + 0) * NION + i) * NPART + ke];
            float a11 = Ag[((1 * 3 + 1) * NION + i) * NPART + ke];
            float a12 = Ag[((1 * 3 + 2) * NION + i) * NPART + ke];
            float a20 = Ag[((2 * 3 + 0) * NION + i) * NPART + ke];
            float a21 = Ag[((2 * 3 + 1) * NION + i) * NPART + ke];
            float a22 = Ag[((2 * 3 + 2) * NION + i) * NPART + ke];
            G0[i] = a00 * a00 + a01 * a01 + a02 * a02;
            G1[i] = a10 * a10 + a11 * a11 + a12 * a12;
            G2[i] = a20 * a20 + a21 * a21 + a22 * a22;
            G3[i] = a00 * a10 + a01 * a11 + a02 * a12;
            G4[i] = a00 * a20 + a01 * a21 + a02 * a22;
            G5[i] = a10 * a20 + a11 * a21 + a12 * a22;
            wir[i] = WI[(size_t)s * (NION * NPART) + i * NPART + ke];
        }
        #pragma unroll
        for (int ib = 0; ib < 4; ++ib) {
            const float* rs = ls + RS_OFF + ib * 384;
            float ev = 0.f;
            #pragma unroll
            for (int i = 0; i < 8; ++i) {
                float r0 = rs[(i * 3 + 0) * 16 + jr];
                float r1 = rs[(i * 3 + 1) * 16 + jr];
                float r2 = rs[(i * 3 + 2) * 16 + jr];
                float ss = r0 * r0 * G0[i];
                ss = fmaf(r1 * r1, G1[i], ss);
                ss = fmaf(r2 * r2, G2[i], ss);
                float tcr = r0 * r1 * G3[i];
                tcr = fmaf(r0 * r2, G4[i], tcr);
                tcr = fmaf(r1 * r2, G5[i], tcr);
                ss = fmaf(2.f, tcr, ss);
                ss = fmaxf(ss, 0.f);
                ev = fmaf(wir[i], __expf(-__builtin_amdgcn_sqrtf(ss)), ev);
            }
            ls[ENV_OFF + (ib * 16 + jr) * 20 + ke] = ev;
        }
    }
    __syncthreads();   // barrier 2: LIN + ENV ready

    // ---- det: 4 matrices per thread-group, 4-way ILP, bpermute broadcast ----
    float Mr[4][16];
    #pragma unroll
    for (int ib = 0; ib < 4; ++ib) {
        const float* lp = ls + LINP_OFF + (ib * 16 + ke) * 16;   // broadcast reads
        const float* lj = ls + LINJ_OFF + (ib * 16 + jr) * 20;
        const float* ev = ls + ENV_OFF  + (ib * 16 + jr) * 20;
        #pragma unroll
        for (int cq = 0; cq < 4; ++cq) {
            float4 a  = *(const float4*)(lp + cq * 4);
            float4 bb = *(const float4*)(lj + cq * 4);
            float4 e  = *(const float4*)(ev + cq * 4);
            Mr[ib][cq * 4 + 0] = (a.x + bb.x) * e.x;
            Mr[ib][cq * 4 + 1] = (a.y + bb.y) * e.y;
            Mr[ib][cq * 4 + 2] = (a.z + bb.z) * e.z;
            Mr[ib][cq * 4 + 3] = (a.w + bb.w) * e.w;
        }
    }
    {
        float detv[4] = {1.f, 1.f, 1.f, 1.f};
        unsigned sel[4] = {0u, 0u, 0u, 0u};
        int inv[4] = {0, 0, 0, 0};
        bool msel[4] = {false, false, false, false};
        const int lanebase4 = (t & 48) << 2;     // byte addr of group base lane
        #pragma unroll
        for (int cc = 0; cc < 16; ++cc) {
            // packed argmax over rows, 4 independent DPP chains (VALU)
            unsigned key[4];
            #pragma unroll
            for (int ib = 0; ib < 4; ++ib)
                key[ib] = msel[ib] ? 0u
                    : ((__float_as_uint(fabsf(Mr[ib][cc])) & 0xFFFFFFF0u) | (unsigned)jr);
            #pragma unroll
            for (int ib = 0; ib < 4; ++ib) { DPPMAXU(key[ib], 0x121); }
            #pragma unroll
            for (int ib = 0; ib < 4; ++ib) { DPPMAXU(key[ib], 0x122); }
            #pragma unroll
            for (int ib = 0; ib < 4; ++ib) { DPPMAXU(key[ib], 0x124); }
            #pragma unroll
            for (int ib = 0; ib < 4; ++ib) { DPPMAXU(key[ib], 0x128); }
            #pragma unroll
            for (int ib = 0; ib < 4; ++ib) {
                const int idx = (int)(key[ib] & 15u);
                const bool ispiv = (jr == idx) && !msel[ib];
                const int srcaddr = lanebase4 | (idx << 2);
                // pivot-row broadcast on the LDS permute pipe (1 op/element)
                float Pr[16];
                #pragma unroll
                for (int k2 = cc; k2 < 16; ++k2)
                    Pr[k2] = __int_as_float(__builtin_amdgcn_ds_bpermute(
                                 srcaddr, __float_as_int(Mr[ib][k2])));
                const float pv = Pr[cc];
                const float f = (msel[ib] || ispiv || pv == 0.f) ? 0.f
                              : Mr[ib][cc] * __builtin_amdgcn_rcpf(pv);
                inv[ib] += __popc(sel[ib] >> (idx + 1));
                sel[ib] |= (1u << idx);
                msel[ib] = msel[ib] || ispiv;
                detv[ib] *= pv;
                #pragma unroll
                for (int k2 = cc + 1; k2 < 16; ++k2)
                    Mr[ib][k2] = fmaf(-f, Pr[k2], Mr[ib][k2]);
            }
        }
        #pragma unroll
        for (int ib = 0; ib < 4; ++ib) {
            if (inv[ib] & 1) detv[ib] = -detv[ib];
            if (jr == 0) ls[DETS_OFF + ib * 16 + ke] = detv[ib];
        }
    }
    __syncthreads();   // barrier 3: DETS ready

    // ---- epilogue: out = x * det, coalesced float4 ----
    #pragma unroll
    for (int ib = 0; ib < 4; ++ib) {
        const size_t base = ((size_t)(b0 + ib) * 32 + s * 16) * DDIM;
        #pragma unroll
        for (int i2 = 0; i2 < 8; ++i2) {
            int f4i = i2 * 256 + t;
            float dt = ls[DETS_OFF + ib * 16 + (f4i >> 7)];
            float4 xv = ((const float4*)(EQ + base))[f4i];
            float4 o = make_float4(xv.x * dt, xv.y * dt, xv.z * dt, xv.w * dt);
            ((float4*)(OUT + base))[f4i] = o;
        }
    }
}

extern "C" void kernel_launch(void* const* d_in, const int* in_sizes, int n_in,
                              void* d_out, int out_size, void* d_ws, size_t ws_size,
                              hipStream_t stream) {
    const float* EQ = (const float*)d_in[0];
    const float* RE = (const float*)d_in[1];
    const float* WL = (const float*)d_in[2];
    const float* BL = (const float*)d_in[3];
    const float* AE = (const float*)d_in[4];
    const float* WI = (const float*)d_in[5];
    float* OUT = (float*)d_out;
    (void)in_sizes; (void)n_in; (void)out_size; (void)d_ws; (void)ws_size;

    hipFuncSetAttribute((const void*)ppdet_kernel,
                        hipFuncAttributeMaxDynamicSharedMemorySize, LDS_BYTES);
    ppdet_kernel<<<dim3(1024), dim3(256), LDS_BYTES, stream>>>(EQ, RE, WL, BL, AE, WI, OUT);
}

// Round 5
// 86.388 us; speedup vs baseline: 3.9119x; 3.9119x over previous
//
#include <hip/hip_runtime.h>
#include <cstdint>
#include <cstddef>

#define NSPIN 2
#define NPART 16
#define DDIM  512
#define NION  8

// LDS float offsets (total 13376 floats = 53504 B -> 3 blocks/CU)
#define RS_OFF    8192                   // bf16 W fragments occupy [0,8192) floats = 32 KB
#define LINP_OFF  (RS_OFF + 1536)        // RS: [ib][e(24)][j(16)] = 1536
#define LINJ_OFF  (LINP_OFF + 1024)      // LINP: [ib][p][k] stride 16
#define ENV_OFF   (LINJ_OFF + 1280)      // LINJ: [ib][j][k] stride 20
#define DETS_OFF  (ENV_OFF + 1280)       // ENV:  [ib][j][k] stride 20
#define LDS_FLOATS (DETS_OFF + 64)
#define LDS_BYTES  (LDS_FLOATS * 4)      // 53504 B

typedef short bf16x8 __attribute__((ext_vector_type(8)));
typedef float f32x4  __attribute__((ext_vector_type(4)));

__device__ __forceinline__ short bfc(float x) {  // f32 -> bf16 (RNE)
    unsigned u = __float_as_uint(x);
    u += 0x7FFFu + ((u >> 16) & 1u);
    return (short)(u >> 16);
}

// 16-lane-row rotate + unsigned max (VALU pipe)
#define DPPMAXU(k, ctrl) { unsigned o_ = (unsigned)__builtin_amdgcn_update_dpp(0, (int)(k), (ctrl), 0xF, 0xF, true); (k) = (k) > o_ ? (k) : o_; }

__global__ void __launch_bounds__(256, 3)
ppdet_kernel(const float* __restrict__ EQ, const float* __restrict__ RE,
             const float* __restrict__ WL, const float* __restrict__ BL,
             const float* __restrict__ AE, const float* __restrict__ WI,
             float* __restrict__ OUT)
{
    extern __shared__ float ls[];
    const int t  = threadIdx.x;
    const int s  = blockIdx.x >> 9;           // spin
    const int b0 = (blockIdx.x & 511) * 4;    // 4 b's per block

    const int l  = t & 63;                    // lane in wave
    const int w  = t >> 6;                    // wave id (0..3)
    const int c  = l & 15;                    // MFMA row/col lane index
    const int h4 = l >> 4;                    // MFMA k-group
    const int jr = t & 15;                    // row index (env/det)
    const int ke = t >> 4;                    // k-column slot (env) / matrix p (det)

    // ---- stage W as bf16 MFMA B-fragments: slot = (half*16+ks)*64+lane ----
    {
        const float* Wg = WL + (size_t)s * (2 * DDIM * NPART);
        ushort* wb = (ushort*)ls;
        #pragma unroll
        for (int it = 0; it < 8; ++it) {
            int slot = it * 256 + t;              // 0..2047
            int half = slot >> 10;
            int ks   = (slot >> 6) & 15;
            int lane = slot & 63;
            int cc2  = lane & 15, hh = lane >> 4;
            const float* src = Wg + ((size_t)(half * 512 + ks * 32 + hh * 8)) * NPART + cc2;
            ushort u[8];
            #pragma unroll
            for (int e = 0; e < 8; ++e) u[e] = (ushort)bfc(src[e * NPART]);
            uint4 pk;
            pk.x = (unsigned)u[0] | ((unsigned)u[1] << 16);
            pk.y = (unsigned)u[2] | ((unsigned)u[3] << 16);
            pk.z = (unsigned)u[4] | ((unsigned)u[5] << 16);
            pk.w = (unsigned)u[6] | ((unsigned)u[7] << 16);
            *(uint4*)&wb[slot * 8] = pk;
        }
    }
    // ---- stage r_ei transposed: RS[ib][e][j], lane-linear writes ----
    #pragma unroll
    for (int it = 0; it < 6; ++it) {
        int idx = it * 256 + t;                   // 0..1535 = ib*384 + e*16 + j
        int bi = idx / 384, rem = idx % 384;
        int e = rem >> 4, j = rem & 15;
        ls[RS_OFF + idx] = RE[((size_t)(b0 + bi) * 32 + s * 16 + j) * 24 + e];
    }
    __syncthreads();   // barrier 1: W + RS staged

    // ---- GEMM via MFMA: wave w handles b = b0+w ----
    {
        const float* xg = EQ + ((size_t)(b0 + w) * 32 + s * 16 + c) * DDIM + h4 * 8;
        const ushort* wb = (const ushort*)ls;
        f32x4 accp = {0.f, 0.f, 0.f, 0.f}, accj = {0.f, 0.f, 0.f, 0.f};
        #pragma unroll
        for (int ks = 0; ks < 16; ++ks) {
            float4 a0 = *(const float4*)(xg + ks * 32);
            float4 a1 = *(const float4*)(xg + ks * 32 + 4);
            bf16x8 af;
            af[0] = bfc(a0.x); af[1] = bfc(a0.y); af[2] = bfc(a0.z); af[3] = bfc(a0.w);
            af[4] = bfc(a1.x); af[5] = bfc(a1.y); af[6] = bfc(a1.z); af[7] = bfc(a1.w);
            bf16x8 bf1 = *(const bf16x8*)(wb + (size_t)(ks * 64 + l) * 8);
            bf16x8 bf2 = *(const bf16x8*)(wb + (size_t)((16 + ks) * 64 + l) * 8);
            accp = __builtin_amdgcn_mfma_f32_16x16x32_bf16(af, bf1, accp, 0, 0, 0);
            accj = __builtin_amdgcn_mfma_f32_16x16x32_bf16(af, bf2, accj, 0, 0, 0);
        }
        const float blv = BL[s * NPART + c];
        #pragma unroll
        for (int q = 0; q < 4; ++q) {     // C: row = h4*4+q, col = c
            ls[LINP_OFF + (w * 16 + h4 * 4 + q) * 16 + c] = accp[q];
            ls[LINJ_OFF + (w * 16 + h4 * 4 + q) * 20 + c] = accj[q] + blv;
        }
    }

    // ---- env: Gram trick, G = A^T A per (ion, ke); RS reads conflict-free ----
    {
        float G0[8], G1[8], G2[8], G3[8], G4[8], G5[8], wir[8];
        const float* Ag = AE + (size_t)s * (9 * NION * NPART);
        #pragma unroll
        for (int i = 0; i < 8; ++i) {
            float a00 = Ag[((0 * 3 + 0) * NION + i) * NPART + ke];
            float a01 = Ag[((0 * 3 + 1) * NION + i) * NPART + ke];
            float a02 = Ag[((0 * 3 + 2) * NION + i) * NPART + ke];
            float a10 = Ag[((1 * 3 + 0) * NION + i) * NPART + ke];
            float a11 = Ag[((1 * 3 + 1) * NION + i) * NPART + ke];
            float a12 = Ag[((1 * 3 + 2) * NION + i) * NPART + ke];
            float a20 = Ag[((2 * 3 + 0) * NION + i) * NPART + ke];
            float a21 = Ag[((2 * 3 + 1) * NION + i) * NPART + ke];
            float a22 = Ag[((2 * 3 + 2) * NION + i) * NPART + ke];
            G0[i] = a00 * a00 + a01 * a01 + a02 * a02;
            G1[i] = a10 * a10 + a11 * a11 + a12 * a12;
            G2[i] = a20 * a20 + a21 * a21 + a22 * a22;
            G3[i] = a00 * a10 + a01 * a11 + a02 * a12;
            G4[i] = a00 * a20 + a01 * a21 + a02 * a22;
            G5[i] = a10 * a20 + a11 * a21 + a12 * a22;
            wir[i] = WI[(size_t)s * (NION * NPART) + i * NPART + ke];
        }
        #pragma unroll
        for (int ib = 0; ib < 4; ++ib) {
            const float* rs = ls + RS_OFF + ib * 384;
            float ev = 0.f;
            #pragma unroll
            for (int i = 0; i < 8; ++i) {
                float r0 = rs[(i * 3 + 0) * 16 + jr];
                float r1 = rs[(i * 3 + 1) * 16 + jr];
                float r2 = rs[(i * 3 + 2) * 16 + jr];
                float ss = r0 * r0 * G0[i];
                ss = fmaf(r1 * r1, G1[i], ss);
                ss = fmaf(r2 * r2, G2[i], ss);
                float tcr = r0 * r1 * G3[i];
                tcr = fmaf(r0 * r2, G4[i], tcr);
                tcr = fmaf(r1 * r2, G5[i], tcr);
                ss = fmaf(2.f, tcr, ss);
                ss = fmaxf(ss, 0.f);
                ev = fmaf(wir[i], __expf(-__builtin_amdgcn_sqrtf(ss)), ev);
            }
            ls[ENV_OFF + (ib * 16 + jr) * 20 + ke] = ev;
        }
    }
    __syncthreads();   // barrier 2: LIN + ENV ready

    // ---- det: sequential over 4 matrices (low reg pressure), bpermute broadcast ----
    const int lanebase4 = (t & 48) << 2;     // byte addr of group base lane
    for (int ib = 0; ib < 4; ++ib) {
        float Mr[16];
        const float* lp = ls + LINP_OFF + (ib * 16 + ke) * 16;   // broadcast reads
        const float* lj = ls + LINJ_OFF + (ib * 16 + jr) * 20;
        const float* ev = ls + ENV_OFF  + (ib * 16 + jr) * 20;
        #pragma unroll
        for (int cq = 0; cq < 4; ++cq) {
            float4 a  = *(const float4*)(lp + cq * 4);
            float4 bb = *(const float4*)(lj + cq * 4);
            float4 e  = *(const float4*)(ev + cq * 4);
            Mr[cq * 4 + 0] = (a.x + bb.x) * e.x;
            Mr[cq * 4 + 1] = (a.y + bb.y) * e.y;
            Mr[cq * 4 + 2] = (a.z + bb.z) * e.z;
            Mr[cq * 4 + 3] = (a.w + bb.w) * e.w;
        }
        float detv = 1.f;
        unsigned sel = 0u;
        int inv = 0;
        bool msel = false;
        #pragma unroll
        for (int cc = 0; cc < 16; ++cc) {
            // packed argmax over unselected rows (DPP, VALU-only)
            unsigned key = msel ? 0u
                : ((__float_as_uint(fabsf(Mr[cc])) & 0xFFFFFFF0u) | (unsigned)jr);
            DPPMAXU(key, 0x121); DPPMAXU(key, 0x122); DPPMAXU(key, 0x124); DPPMAXU(key, 0x128);
            const int idx = (int)(key & 15u);
            const bool ispiv = (jr == idx) && !msel;
            const int srcaddr = lanebase4 | (idx << 2);
            // pivot-row broadcast on the LDS permute pipe (1 op/element)
            float Pr[16];
            #pragma unroll
            for (int k2 = cc; k2 < 16; ++k2)
                Pr[k2] = __int_as_float(__builtin_amdgcn_ds_bpermute(
                             srcaddr, __float_as_int(Mr[k2])));
            const float pv = Pr[cc];
            const float f = (msel || ispiv || pv == 0.f) ? 0.f
                          : Mr[cc] * __builtin_amdgcn_rcpf(pv);
            inv += __popc(sel >> (idx + 1));
            sel |= (1u << idx);
            msel = msel || ispiv;
            detv *= pv;
            #pragma unroll
            for (int k2 = cc + 1; k2 < 16; ++k2)
                Mr[k2] = fmaf(-f, Pr[k2], Mr[k2]);
        }
        if (inv & 1) detv = -detv;
        if (jr == 0) ls[DETS_OFF + ib * 16 + ke] = detv;
    }
    __syncthreads();   // barrier 3: DETS ready

    // ---- epilogue: out = x * det, coalesced float4 ----
    #pragma unroll
    for (int ib = 0; ib < 4; ++ib) {
        const size_t base = ((size_t)(b0 + ib) * 32 + s * 16) * DDIM;
        #pragma unroll
        for (int i2 = 0; i2 < 8; ++i2) {
            int f4i = i2 * 256 + t;
            float dt = ls[DETS_OFF + ib * 16 + (f4i >> 7)];
            float4 xv = ((const float4*)(EQ + base))[f4i];
            float4 o = make_float4(xv.x * dt, xv.y * dt, xv.z * dt, xv.w * dt);
            ((float4*)(OUT + base))[f4i] = o;
        }
    }
}

extern "C" void kernel_launch(void* const* d_in, const int* in_sizes, int n_in,
                              void* d_out, int out_size, void* d_ws, size_t ws_size,
                              hipStream_t stream) {
    const float* EQ = (const float*)d_in[0];
    const float* RE = (const float*)d_in[1];
    const float* WL = (const float*)d_in[2];
    const float* BL = (const float*)d_in[3];
    const float* AE = (const float*)d_in[4];
    const float* WI = (const float*)d_in[5];
    float* OUT = (float*)d_out;
    (void)in_sizes; (void)n_in; (void)out_size; (void)d_ws; (void)ws_size;

    hipFuncSetAttribute((const void*)ppdet_kernel,
                        hipFuncAttributeMaxDynamicSharedMemorySize, LDS_BYTES);
    ppdet_kernel<<<dim3(1024), dim3(256), LDS_BYTES, stream>>>(EQ, RE, WL, BL, AE, WI, OUT);
}

// Round 6
// 76.330 us; speedup vs baseline: 4.4274x; 1.1318x over previous
//
#include <hip/hip_runtime.h>
#include <cstdint>
#include <cstddef>

#define NSPIN 2
#define NPART 16
#define DDIM  512
#define NION  8

// LDS float offsets (total 5184 floats = 20736 B -> 7 blocks/CU)
#define RS_OFF    0                      // RS: [ib][e(24)][j(16)] = 1536
#define LINP_OFF  1536                   // LINP: [ib][p][k] stride 16 = 1024
#define LINJ_OFF  (LINP_OFF + 1024)      // LINJ: [ib][j][k] stride 20 = 1280
#define ENV_OFF   (LINJ_OFF + 1280)      // ENV:  [ib][j][k] stride 20 = 1280
#define DETS_OFF  (ENV_OFF + 1280)       // 64
#define LDS_FLOATS (DETS_OFF + 64)
#define LDS_BYTES  (LDS_FLOATS * 4)      // 20736 B

typedef short bf16x8 __attribute__((ext_vector_type(8)));
typedef float f32x4  __attribute__((ext_vector_type(4)));

__device__ __forceinline__ short bfc(float x) {  // f32 -> bf16 (RNE)
    unsigned u = __float_as_uint(x);
    u += 0x7FFFu + ((u >> 16) & 1u);
    return (short)(u >> 16);
}

// 16-lane-row rotate + unsigned max (VALU pipe)
#define DPPMAXU(k, ctrl) { unsigned o_ = (unsigned)__builtin_amdgcn_update_dpp(0, (int)(k), (ctrl), 0xF, 0xF, true); (k) = (k) > o_ ? (k) : o_; }

// ---- prep: WL (2,1024,16) f32 -> bf16 B-fragments in ws ----
// slot = ((spin*2 + half)*16 + ks)*64 + lane ; each slot = 8 bf16 (16 B)
__global__ void __launch_bounds__(256)
prep_kernel(const float* __restrict__ WL, uint4* __restrict__ WS)
{
    int slot = blockIdx.x * 256 + threadIdx.x;       // 0..4095
    int spin = slot >> 11;
    int rem  = slot & 2047;
    int half = rem >> 10;
    int ks   = (rem >> 6) & 15;
    int lane = rem & 63;
    int cc2  = lane & 15, hh = lane >> 4;
    const float* src = WL + (size_t)spin * (2 * DDIM * NPART)
                     + ((size_t)(half * 512 + ks * 32 + hh * 8)) * NPART + cc2;
    ushort u[8];
    #pragma unroll
    for (int e = 0; e < 8; ++e) u[e] = (ushort)bfc(src[e * NPART]);
    uint4 pk;
    pk.x = (unsigned)u[0] | ((unsigned)u[1] << 16);
    pk.y = (unsigned)u[2] | ((unsigned)u[3] << 16);
    pk.z = (unsigned)u[4] | ((unsigned)u[5] << 16);
    pk.w = (unsigned)u[6] | ((unsigned)u[7] << 16);
    WS[slot] = pk;
}

__global__ void __launch_bounds__(256, 5)
ppdet_kernel(const float* __restrict__ EQ, const float* __restrict__ RE,
             const uint4* __restrict__ WS, const float* __restrict__ BL,
             const float* __restrict__ AE, const float* __restrict__ WI,
             float* __restrict__ OUT)
{
    extern __shared__ float ls[];
    const int t  = threadIdx.x;
    const int s  = blockIdx.x >> 9;           // spin
    const int b0 = (blockIdx.x & 511) * 4;    // 4 b's per block

    const int l  = t & 63;                    // lane in wave
    const int w  = t >> 6;                    // wave id (0..3)
    const int c  = l & 15;                    // MFMA row/col lane index
    const int h4 = l >> 4;                    // MFMA k-group
    const int jr = t & 15;                    // row index (env/det)
    const int ke = t >> 4;                    // k-column slot (env) / matrix p (det)

    // ---- stage r_ei transposed: RS[ib][e][j], lane-linear writes ----
    #pragma unroll
    for (int it = 0; it < 6; ++it) {
        int idx = it * 256 + t;                   // 0..1535 = ib*384 + e*16 + j
        int bi = idx / 384, rem = idx % 384;
        int e = rem >> 4, j = rem & 15;
        ls[RS_OFF + idx] = RE[((size_t)(b0 + bi) * 32 + s * 16 + j) * 24 + e];
    }
    __syncthreads();   // barrier 1: RS staged

    // ---- GEMM via MFMA: wave w handles b = b0+w; W fragments from global (L2) ----
    {
        const float* xg = EQ + ((size_t)(b0 + w) * 32 + s * 16 + c) * DDIM + h4 * 8;
        const uint4* wb = WS + (size_t)s * 2048;   // [half*16+ks]*64 + l
        f32x4 accp = {0.f, 0.f, 0.f, 0.f}, accj = {0.f, 0.f, 0.f, 0.f};
        #pragma unroll
        for (int kb = 0; kb < 4; ++kb) {
            float4 xa[8];
            uint4 w1v[4], w2v[4];
            #pragma unroll
            for (int u = 0; u < 4; ++u) {
                xa[2 * u]     = *(const float4*)(xg + (kb * 4 + u) * 32);
                xa[2 * u + 1] = *(const float4*)(xg + (kb * 4 + u) * 32 + 4);
                w1v[u] = wb[(kb * 4 + u) * 64 + l];
                w2v[u] = wb[(16 + kb * 4 + u) * 64 + l];
            }
            #pragma unroll
            for (int u = 0; u < 4; ++u) {
                bf16x8 af;
                af[0] = bfc(xa[2 * u].x);     af[1] = bfc(xa[2 * u].y);
                af[2] = bfc(xa[2 * u].z);     af[3] = bfc(xa[2 * u].w);
                af[4] = bfc(xa[2 * u + 1].x); af[5] = bfc(xa[2 * u + 1].y);
                af[6] = bfc(xa[2 * u + 1].z); af[7] = bfc(xa[2 * u + 1].w);
                accp = __builtin_amdgcn_mfma_f32_16x16x32_bf16(af, *(bf16x8*)&w1v[u], accp, 0, 0, 0);
                accj = __builtin_amdgcn_mfma_f32_16x16x32_bf16(af, *(bf16x8*)&w2v[u], accj, 0, 0, 0);
            }
        }
        const float blv = BL[s * NPART + c];
        #pragma unroll
        for (int q = 0; q < 4; ++q) {     // C: row = h4*4+q, col = c
            ls[LINP_OFF + (w * 16 + h4 * 4 + q) * 16 + c] = accp[q];
            ls[LINJ_OFF + (w * 16 + h4 * 4 + q) * 20 + c] = accj[q] + blv;
        }
    }

    // ---- env: Gram trick, G = A^T A per (ion, ke); RS reads conflict-free ----
    {
        float G0[8], G1[8], G2[8], G3[8], G4[8], G5[8], wir[8];
        const float* Ag = AE + (size_t)s * (9 * NION * NPART);
        #pragma unroll
        for (int i = 0; i < 8; ++i) {
            float a00 = Ag[((0 * 3 + 0) * NION + i) * NPART + ke];
            float a01 = Ag[((0 * 3 + 1) * NION + i) * NPART + ke];
            float a02 = Ag[((0 * 3 + 2) * NION + i) * NPART + ke];
            float a10 = Ag[((1 * 3 + 0) * NION + i) * NPART + ke];
            float a11 = Ag[((1 * 3 + 1) * NION + i) * NPART + ke];
            float a12 = Ag[((1 * 3 + 2) * NION + i) * NPART + ke];
            float a20 = Ag[((2 * 3 + 0) * NION + i) * NPART + ke];
            float a21 = Ag[((2 * 3 + 1) * NION + i) * NPART + ke];
            float a22 = Ag[((2 * 3 + 2) * NION + i) * NPART + ke];
            G0[i] = a00 * a00 + a01 * a01 + a02 * a02;
            G1[i] = a10 * a10 + a11 * a11 + a12 * a12;
            G2[i] = a20 * a20 + a21 * a21 + a22 * a22;
            G3[i] = a00 * a10 + a01 * a11 + a02 * a12;
            G4[i] = a00 * a20 + a01 * a21 + a02 * a22;
            G5[i] = a10 * a20 + a11 * a21 + a12 * a22;
            wir[i] = WI[(size_t)s * (NION * NPART) + i * NPART + ke];
        }
        #pragma unroll
        for (int ib = 0; ib < 4; ++ib) {
            const float* rs = ls + RS_OFF + ib * 384;
            float ev = 0.f;
            #pragma unroll
            for (int i = 0; i < 8; ++i) {
                float r0 = rs[(i * 3 + 0) * 16 + jr];
                float r1 = rs[(i * 3 + 1) * 16 + jr];
                float r2 = rs[(i * 3 + 2) * 16 + jr];
                float ss = r0 * r0 * G0[i];
                ss = fmaf(r1 * r1, G1[i], ss);
                ss = fmaf(r2 * r2, G2[i], ss);
                float tcr = r0 * r1 * G3[i];
                tcr = fmaf(r0 * r2, G4[i], tcr);
                tcr = fmaf(r1 * r2, G5[i], tcr);
                ss = fmaf(2.f, tcr, ss);
                ss = fmaxf(ss, 0.f);
                ev = fmaf(wir[i], __expf(-__builtin_amdgcn_sqrtf(ss)), ev);
            }
            ls[ENV_OFF + (ib * 16 + jr) * 20 + ke] = ev;
        }
    }
    __syncthreads();   // barrier 2: LIN + ENV ready

    // ---- det: sequential over 4 matrices (low reg pressure), bpermute broadcast ----
    const int lanebase4 = (t & 48) << 2;     // byte addr of group base lane
    for (int ib = 0; ib < 4; ++ib) {
        float Mr[16];
        const float* lp = ls + LINP_OFF + (ib * 16 + ke) * 16;   // broadcast reads
        const float* lj = ls + LINJ_OFF + (ib * 16 + jr) * 20;
        const float* ev = ls + ENV_OFF  + (ib * 16 + jr) * 20;
        #pragma unroll
        for (int cq = 0; cq < 4; ++cq) {
            float4 a  = *(const float4*)(lp + cq * 4);
            float4 bb = *(const float4*)(lj + cq * 4);
            float4 e  = *(const float4*)(ev + cq * 4);
            Mr[cq * 4 + 0] = (a.x + bb.x) * e.x;
            Mr[cq * 4 + 1] = (a.y + bb.y) * e.y;
            Mr[cq * 4 + 2] = (a.z + bb.z) * e.z;
            Mr[cq * 4 + 3] = (a.w + bb.w) * e.w;
        }
        float detv = 1.f;
        unsigned sel = 0u;
        int inv = 0;
        bool msel = false;
        #pragma unroll
        for (int cc = 0; cc < 16; ++cc) {
            // packed argmax over unselected rows (DPP, VALU-only)
            unsigned key = msel ? 0u
                : ((__float_as_uint(fabsf(Mr[cc])) & 0xFFFFFFF0u) | (unsigned)jr);
            DPPMAXU(key, 0x121); DPPMAXU(key, 0x122); DPPMAXU(key, 0x124); DPPMAXU(key, 0x128);
            const int idx = (int)(key & 15u);
            const bool ispiv = (jr == idx) && !msel;
            const int srcaddr = lanebase4 | (idx << 2);
            // pivot-row broadcast on the LDS permute pipe (1 op/element)
            float Pr[16];
            #pragma unroll
            for (int k2 = cc; k2 < 16; ++k2)
                Pr[k2] = __int_as_float(__builtin_amdgcn_ds_bpermute(
                             srcaddr, __float_as_int(Mr[k2])));
            const float pv = Pr[cc];
            const float f = (msel || ispiv || pv == 0.f) ? 0.f
                          : Mr[cc] * __builtin_amdgcn_rcpf(pv);
            inv += __popc(sel >> (idx + 1));
            sel |= (1u << idx);
            msel = msel || ispiv;
            detv *= pv;
            #pragma unroll
            for (int k2 = cc + 1; k2 < 16; ++k2)
                Mr[k2] = fmaf(-f, Pr[k2], Mr[k2]);
        }
        if (inv & 1) detv = -detv;
        if (jr == 0) ls[DETS_OFF + ib * 16 + ke] = detv;
    }
    __syncthreads();   // barrier 3: DETS ready

    // ---- epilogue: out = x * det, coalesced float4 ----
    #pragma unroll
    for (int ib = 0; ib < 4; ++ib) {
        const size_t base = ((size_t)(b0 + ib) * 32 + s * 16) * DDIM;
        #pragma unroll
        for (int i2 = 0; i2 < 8; ++i2) {
            int f4i = i2 * 256 + t;
            float dt = ls[DETS_OFF + ib * 16 + (f4i >> 7)];
            float4 xv = ((const float4*)(EQ + base))[f4i];
            float4 o = make_float4(xv.x * dt, xv.y * dt, xv.z * dt, xv.w * dt);
            ((float4*)(OUT + base))[f4i] = o;
        }
    }
}

extern "C" void kernel_launch(void* const* d_in, const int* in_sizes, int n_in,
                              void* d_out, int out_size, void* d_ws, size_t ws_size,
                              hipStream_t stream) {
    const float* EQ = (const float*)d_in[0];
    const float* RE = (const float*)d_in[1];
    const float* WL = (const float*)d_in[2];
    const float* BL = (const float*)d_in[3];
    const float* AE = (const float*)d_in[4];
    const float* WI = (const float*)d_in[5];
    float* OUT = (float*)d_out;
    uint4* WS = (uint4*)d_ws;   // 4096 slots * 16 B = 64 KB
    (void)in_sizes; (void)n_in; (void)out_size; (void)ws_size;

    prep_kernel<<<dim3(16), dim3(256), 0, stream>>>(WL, WS);
    ppdet_kernel<<<dim3(1024), dim3(256), LDS_BYTES, stream>>>(EQ, RE, WS, BL, AE, WI, OUT);
}